// Round 1
// baseline (452.495 us; speedup 1.0000x reference)
//
// AttentionPropagation — fused bf16-MFMA flash attention for MI355X (gfx950).
//
// Structure:
//   prep_kv  (64 blocks): K = Wk·[feat,xyz]+bk (bf16, row-major), V^T = (Wv·feat+bv)^T
//            (bf16, [128][4096]), extK[16] = split-bf16 coord vector for the
//            distance-bias MFMA.  All via 32x32x16 bf16 MFMA.
//   attn_fwd (512 blocks, 4 waves, 32 queries/wave): fused Q-projection (MFMA),
//            flash loop over 128 key-tiles of 32:
//              sq-MFMA (C-init=|q|^2) -> bias=-0.5*sqrt(sq) -> 8 QK MFMAs (C-init=bias)
//              -> online softmax (partner lanes l,l^32 share a query) -> P->B-frag
//              conversion (pk2 + shfl_xor(32)) -> 8 PV MFMAs.
//            Epilogue: out^T = Wo_h·(O/l) + [Wo_h·feat_h + Wo_h·feat_l + Wo_l·feat_h] + bo
//            (split-bf16 keeps the feat residual path exact to ~1e-5), stored with
//            full 64B-sector efficiency directly from C-layout quads.
// LDS: 16KB (K tile 32x128 bf16 XOR(r&7)-swizzled; V^T tile 128x32 XOR(r&3)-swizzled),
//      both conflict-free for the MFMA ds_read_b128 patterns (checked by slot-mod-8 analysis).
// ws usage: 4.25 MB (K 2MB | V^T 2MB | extK 256KB), rewritten every launch.
// Next rungs (not this round): global_load_lds staging, KT=64, 8-phase counted-vmcnt,
// permlane32_swap instead of shfl_xor, s_setprio around MFMA clusters.

#include <hip/hip_runtime.h>
#include <stdint.h>

#define NB 2
#define N1 4096
#define N2 32768
#define DD 128
#define KT 32
#define NTILES (N1 / KT)
static constexpr float SCL = 0.08838834764831845f; // 1/sqrt(128)

typedef float f32x16 __attribute__((ext_vector_type(16)));
typedef __bf16 bf16x8v __attribute__((ext_vector_type(8)));
typedef unsigned int u32;
typedef unsigned short u16;

union FragU { uint4 u; bf16x8v b; };

__device__ __forceinline__ u16 f2bf(float f) {
  u32 u = __builtin_bit_cast(u32, f);
  u += 0x7FFFu + ((u >> 16) & 1u); // RNE
  return (u16)(u >> 16);
}
__device__ __forceinline__ u32 pk2(float lo, float hi) {
  return (u32)f2bf(lo) | ((u32)f2bf(hi) << 16);
}
__device__ __forceinline__ float bfhi(float f) { // float value of bf16(f)
  return __builtin_bit_cast(float, (u32)f2bf(f) << 16);
}
__device__ __forceinline__ f32x16 MFMA(uint4 a, uint4 b, const f32x16& c) {
  FragU A, B; A.u = a; B.u = b;
  return __builtin_amdgcn_mfma_f32_32x32x16_bf16(A.b, B.b, c, 0, 0, 0);
}
__device__ __forceinline__ uint4 packhi8(float4 a, float4 b) {
  return make_uint4(pk2(a.x, a.y), pk2(a.z, a.w), pk2(b.x, b.y), pk2(b.z, b.w));
}
__device__ __forceinline__ uint4 packlo8(float4 a, float4 b) {
  return make_uint4(pk2(a.x - bfhi(a.x), a.y - bfhi(a.y)),
                    pk2(a.z - bfhi(a.z), a.w - bfhi(a.w)),
                    pk2(b.x - bfhi(b.x), b.y - bfhi(b.y)),
                    pk2(b.z - bfhi(b.z), b.w - bfhi(b.w)));
}
// C-layout 8-reg chunk -> B-fragment for a K=16 MFMA whose contraction rows are the
// C rows.  C row pattern: d = (i&3) + 8*(i>>2) + 4*h (h = lane>>5).  B-frag element
// (h, j) must hold d' = 8h + j.  Partner exchange via shfl_xor(32).
__device__ __forceinline__ uint4 conv8(float a0, float a1, float a2, float a3,
                                       float a4, float a5, float a6, float a7, int h) {
  u32 A0 = pk2(a0, a1), A1 = pk2(a2, a3);
  u32 B0 = pk2(a4, a5), B1 = pk2(a6, a7);
  u32 A0s = (u32)__shfl_xor((int)A0, 32);
  u32 A1s = (u32)__shfl_xor((int)A1, 32);
  u32 B0s = (u32)__shfl_xor((int)B0, 32);
  u32 B1s = (u32)__shfl_xor((int)B1, 32);
  return h ? make_uint4(B0s, B1s, B0, B1) : make_uint4(A0, A1, A0s, A1s);
}

// ---------------------------------------------------------------------------
// prep_kv: K, V^T, extK into workspace.
// ---------------------------------------------------------------------------
__global__ __launch_bounds__(256) void prep_kv(
    const float* __restrict__ sxyz, const float* __restrict__ sfeat,
    const float* __restrict__ Wk, const float* __restrict__ bk,
    const float* __restrict__ Wv, const float* __restrict__ bv,
    u16* __restrict__ Kws, u16* __restrict__ VTws, u16* __restrict__ EKws) {
  const int tid = threadIdx.x;
  const int l = tid & 63, w = tid >> 6, h = l >> 5, ln = l & 31;
  const int b = blockIdx.x >> 5;           // 32 blocks per batch
  const int kb = (blockIdx.x & 31) * 128;
  const int key = kb + w * 32 + ln;
  const size_t frow = (size_t)(b * N1 + key) * DD;

  // feat B-frags (shared by K and V projections); X' layout = [feat(0..127), xyz(128..130)]
  uint4 xf[8];
#pragma unroll
  for (int s = 0; s < 8; ++s) {
    const float4* fp = (const float4*)(sfeat + frow + s * 16 + h * 8);
    xf[s] = packhi8(fp[0], fp[1]);
  }
  const float* xp = sxyz + (size_t)(b * N1 + key) * 3;
  float sx = xp[0], sy = xp[1], sz = xp[2];
  uint4 x8 = h ? make_uint4(0, 0, 0, 0)
               : make_uint4(pk2(sx, sy), pk2(sz, 0.f), 0u, 0u);

  f32x16 kacc[4], vacc[4];
#pragma unroll
  for (int ot = 0; ot < 4; ++ot)
#pragma unroll
    for (int r = 0; r < 16; ++r) {
      int o = (r & 3) + 8 * (r >> 2) + 4 * h + 32 * ot;
      kacc[ot][r] = bk[o];
      vacc[ot][r] = bv[o];
    }

#pragma unroll
  for (int ot = 0; ot < 4; ++ot) {
    const int out = ln + 32 * ot;
    const float* wkr = Wk + (size_t)out * 131;
    const float* wvr = Wv + (size_t)out * DD;
#pragma unroll
    for (int s = 0; s < 8; ++s) {
      const float* p = wkr + 3 + s * 16 + h * 8;   // feat weights live at cols 3..130
      uint4 wa = make_uint4(pk2(p[0], p[1]), pk2(p[2], p[3]),
                            pk2(p[4], p[5]), pk2(p[6], p[7]));
      kacc[ot] = MFMA(wa, xf[s], kacc[ot]);
      const float4* q = (const float4*)(wvr + s * 16 + h * 8);
      vacc[ot] = MFMA(packhi8(q[0], q[1]), xf[s], vacc[ot]);
    }
    uint4 w8 = h ? make_uint4(0, 0, 0, 0)
                 : make_uint4(pk2(wkr[0], wkr[1]), pk2(wkr[2], 0.f), 0u, 0u);
    kacc[ot] = MFMA(w8, x8, kacc[ot]);
  }

  // stores: K row-major bf16 (contiguous quads), V^T transposed scalar bf16
#pragma unroll
  for (int ot = 0; ot < 4; ++ot) {
#pragma unroll
    for (int rq = 0; rq < 4; ++rq) {
      uint2 kv;
      kv.x = pk2(kacc[ot][rq * 4 + 0], kacc[ot][rq * 4 + 1]);
      kv.y = pk2(kacc[ot][rq * 4 + 2], kacc[ot][rq * 4 + 3]);
      *(uint2*)&Kws[(size_t)(b * N1 + key) * DD + ot * 32 + rq * 8 + h * 4] = kv;
    }
#pragma unroll
    for (int r = 0; r < 16; ++r) {
      int o = (r & 3) + 8 * (r >> 2) + 4 * h + 32 * ot;
      VTws[(size_t)(b * DD + o) * N1 + key] = f2bf(vacc[ot][r]);
    }
  }

  // extK: [xh,xl,xh, yh,yl,yh, zh,zl,zh, k2h,k2l, 0...] pairs with extQ so that
  // sum = |k|^2 - 2 q·k (C-init adds |q|^2).
  if (tid < 128) {
    int k2i = kb + tid;
    const float* xq = sxyz + (size_t)(b * N1 + k2i) * 3;
    float x = xq[0], y = xq[1], z = xq[2];
    float k2 = x * x + y * y + z * z;
    float xh = bfhi(x), xl = x - xh;
    float yh = bfhi(y), yl = y - yh;
    float zh = bfhi(z), zl = z - zh;
    float k2h = bfhi(k2), k2l = k2 - k2h;
    uint4 e0 = make_uint4(pk2(xh, xl), pk2(xh, yh), pk2(yl, yh), pk2(zh, zl));
    uint4 e1 = make_uint4(pk2(zh, k2h), pk2(k2l, 0.f), 0u, 0u);
    uint4* dst = (uint4*)&EKws[(size_t)(b * N1 + k2i) * 16];
    dst[0] = e0;
    dst[1] = e1;
  }
}

// ---------------------------------------------------------------------------
// attn_fwd: fused Q-proj + flash attention + output linear.
// ---------------------------------------------------------------------------
__global__ __launch_bounds__(256, 2) void attn_fwd(
    const float* __restrict__ dxyz, const float* __restrict__ dfeat,
    const float* __restrict__ Wq, const float* __restrict__ bq,
    const float* __restrict__ Wo, const float* __restrict__ bo,
    const u16* __restrict__ Kws, const u16* __restrict__ VTws,
    const u16* __restrict__ EKws, float* __restrict__ out) {
  __shared__ __align__(16) u16 sm[8192];   // [0,4096): K tile 32x128 ; [4096,8192): V^T tile 128x32

  const int tid = threadIdx.x;
  const int l = tid & 63, w = tid >> 6, h = l >> 5, ln = l & 31;
  const int b = blockIdx.x >> 8;
  const int qb = (blockIdx.x & 255) * 128;
  const int qi = qb + w * 32 + ln;
  const int bN1 = b * N1;
  const size_t qrow = (size_t)(b * N2 + qi);

  // ---- extQ (distance-bias B-fragment) + |q|^2
  const float* xp = dxyz + qrow * 3;
  const float qx = xp[0], qy = xp[1], qz = xp[2];
  const float q2 = qx * qx + qy * qy + qz * qz;
  {
  }
  float xh = bfhi(qx), xl = qx - xh, yh = bfhi(qy), yl = qy - yh, zh = bfhi(qz), zl = qz - zh;
  const uint4 eq = h ? make_uint4(pk2(-2.f * zl, 1.f), pk2(1.f, 0.f), 0u, 0u)
                     : make_uint4(pk2(-2.f * xh, -2.f * xh), pk2(-2.f * xl, -2.f * yh),
                                  pk2(-2.f * yh, -2.f * yl), pk2(-2.f * zh, -2.f * zh));

  // ---- Q projection (scaled by 1/sqrt(D)); X' = [feat, xyz]
  uint4 qf[8];
  {
    uint4 xf[8];
#pragma unroll
    for (int s = 0; s < 8; ++s) {
      const float4* fp = (const float4*)(dfeat + qrow * DD + s * 16 + h * 8);
      xf[s] = packhi8(fp[0], fp[1]);
    }
    uint4 x8 = h ? make_uint4(0, 0, 0, 0)
                 : make_uint4(pk2(qx, qy), pk2(qz, 0.f), 0u, 0u);
    f32x16 qt[4];
#pragma unroll
    for (int ot = 0; ot < 4; ++ot) {
#pragma unroll
      for (int r = 0; r < 16; ++r)
        qt[ot][r] = SCL * bq[(r & 3) + 8 * (r >> 2) + 4 * h + 32 * ot];
      const float* wqr = Wq + (size_t)(ln + 32 * ot) * 131;
#pragma unroll
      for (int s = 0; s < 8; ++s) {
        const float* p = wqr + 3 + s * 16 + h * 8;
        uint4 wa = make_uint4(pk2(SCL * p[0], SCL * p[1]), pk2(SCL * p[2], SCL * p[3]),
                              pk2(SCL * p[4], SCL * p[5]), pk2(SCL * p[6], SCL * p[7]));
        qt[ot] = MFMA(wa, xf[s], qt[ot]);
      }
      uint4 w8 = h ? make_uint4(0, 0, 0, 0)
                   : make_uint4(pk2(SCL * wqr[0], SCL * wqr[1]), pk2(SCL * wqr[2], 0.f), 0u, 0u);
      qt[ot] = MFMA(w8, x8, qt[ot]);
    }
    // Q^T C-layout -> QK B-frags: chunk s covers out-dims [16s, 16s+16)
#pragma unroll
    for (int s = 0; s < 8; ++s) {
      const f32x16& c = qt[s >> 1];
      const int br = (s & 1) * 8;
      qf[s] = conv8(c[br + 0], c[br + 1], c[br + 2], c[br + 3],
                    c[br + 4], c[br + 5], c[br + 6], c[br + 7], h);
    }
  }

  f32x16 oacc[4];
#pragma unroll
  for (int ft = 0; ft < 4; ++ft)
#pragma unroll
    for (int r = 0; r < 16; ++r) oacc[ft][r] = 0.f;
  float m = -1e30f, lsum = 0.f;

  uint4 ek = *(const uint4*)&EKws[(size_t)(bN1 + ln) * 16 + h * 8]; // tile 0 prefetch

  for (int t = 0; t < NTILES; ++t) {
    const int kt = t * KT;
    // ---- stage K (XOR r&7 swizzle) and V^T (XOR r&3 swizzle) tiles; coalesced global reads
    {
      int r = tid >> 4, d = tid & 15;
      *(uint4*)&sm[r * 128 + ((d ^ (r & 7)) * 8)] =
          *(const uint4*)&Kws[(size_t)(bN1 + kt + r) * DD + d * 8];
      r += 16;
      *(uint4*)&sm[r * 128 + ((d ^ (r & 7)) * 8)] =
          *(const uint4*)&Kws[(size_t)(bN1 + kt + r) * DD + d * 8];
    }
    {
      int r = tid >> 2, d = tid & 3;
      *(uint4*)&sm[4096 + r * 32 + ((d ^ (r & 3)) * 8)] =
          *(const uint4*)&VTws[(size_t)(b * DD + r) * N1 + kt + d * 8];
      r += 64;
      *(uint4*)&sm[4096 + r * 32 + ((d ^ (r & 3)) * 8)] =
          *(const uint4*)&VTws[(size_t)(b * DD + r) * N1 + kt + d * 8];
    }
    __syncthreads();

    // ---- distance bias: sq = |q|^2 + |k|^2 - 2 q·k  (one K=16 MFMA), then -0.5*sqrt
    f32x16 sacc;
#pragma unroll
    for (int r = 0; r < 16; ++r) sacc[r] = q2;
    sacc = MFMA(ek, eq, sacc);
#pragma unroll
    for (int r = 0; r < 16; ++r) sacc[r] = -0.5f * sqrtf(fmaxf(sacc[r], 1e-12f));

    // prefetch next tile's extK fragment
    {
      const int ktn = (t + 1 < NTILES) ? kt + KT : 0;
      ek = *(const uint4*)&EKws[(size_t)(bN1 + ktn + ln) * 16 + h * 8];
    }

    // ---- S^T = K·Q^T (+bias already in C): 8 MFMAs over D=128
#pragma unroll
    for (int kk = 0; kk < 8; ++kk) {
      const uint4 ka = *(const uint4*)&sm[ln * 128 + (((2 * kk + h) ^ (ln & 7)) * 8)];
      sacc = MFMA(ka, qf[kk], sacc);
    }

    // ---- online softmax (partner lanes l and l^32 hold the other 16 keys of this query)
    float tmax = sacc[0];
#pragma unroll
    for (int r = 1; r < 16; ++r) tmax = fmaxf(tmax, sacc[r]);
    tmax = fmaxf(tmax, __shfl_xor(tmax, 32));
    if (!__all(tmax <= m + 8.f)) {        // defer-max (T13)
      float nm = fmaxf(m, tmax);
      float f = __expf(m - nm);
      lsum *= f;
#pragma unroll
      for (int ft = 0; ft < 4; ++ft)
#pragma unroll
        for (int r = 0; r < 16; ++r) oacc[ft][r] *= f;
      m = nm;
    }
#pragma unroll
    for (int r = 0; r < 16; ++r) {
      float p = __expf(sacc[r] - m);
      sacc[r] = p;
      lsum += p;
    }

    // ---- P -> B-frags, then O^T += V^T · P^T (2 key-chunks x 4 f-tiles)
    const uint4 pf0 = conv8(sacc[0], sacc[1], sacc[2], sacc[3],
                            sacc[4], sacc[5], sacc[6], sacc[7], h);
    const uint4 pf1 = conv8(sacc[8], sacc[9], sacc[10], sacc[11],
                            sacc[12], sacc[13], sacc[14], sacc[15], h);
#pragma unroll
    for (int ft = 0; ft < 4; ++ft) {
      const int r = 32 * ft + ln;
      const uint4 va0 = *(const uint4*)&sm[4096 + r * 32 + (((0 + h) ^ (ln & 3)) * 8)];
      oacc[ft] = MFMA(va0, pf0, oacc[ft]);
      const uint4 va1 = *(const uint4*)&sm[4096 + r * 32 + (((2 + h) ^ (ln & 3)) * 8)];
      oacc[ft] = MFMA(va1, pf1, oacc[ft]);
    }
    __syncthreads();
  }

  // ---- epilogue: out^T = Wo·(O/l) + Wo_h·feat_h + Wo_h·feat_l + Wo_l·feat_h + bo
  lsum += __shfl_xor(lsum, 32);
  const float inv = 1.f / lsum;
#pragma unroll
  for (int ft = 0; ft < 4; ++ft)
#pragma unroll
    for (int r = 0; r < 16; ++r) oacc[ft][r] *= inv;

  f32x16 oc[4];
#pragma unroll
  for (int ot = 0; ot < 4; ++ot)
#pragma unroll
    for (int r = 0; r < 16; ++r)
      oc[ot][r] = bo[(r & 3) + 8 * (r >> 2) + 4 * h + 32 * ot];

#pragma unroll
  for (int s = 0; s < 8; ++s) {
    const f32x16& c = oacc[s >> 1];
    const int br = (s & 1) * 8;
    const uint4 pb = conv8(c[br + 0], c[br + 1], c[br + 2], c[br + 3],
                           c[br + 4], c[br + 5], c[br + 6], c[br + 7], h);
    const float4* fp = (const float4*)(dfeat + qrow * DD + s * 16 + h * 8);
    const float4 fa = fp[0], fb = fp[1];
    const uint4 fh = packhi8(fa, fb);
    const uint4 fl = packlo8(fa, fb);
#pragma unroll
    for (int ot = 0; ot < 4; ++ot) {
      const float4* wp = (const float4*)(Wo + (size_t)(ln + 32 * ot) * DD + s * 16 + h * 8);
      const float4 wa = wp[0], wb = wp[1];
      const uint4 wh = packhi8(wa, wb);
      const uint4 wl = packlo8(wa, wb);
      oc[ot] = MFMA(wh, pb, oc[ot]);
      oc[ot] = MFMA(wh, fh, oc[ot]);
      oc[ot] = MFMA(wh, fl, oc[ot]);
      oc[ot] = MFMA(wl, fh, oc[ot]);
    }
  }

  // ---- store: C-layout quads are contiguous -> full 64B-sector efficiency
  float* orow = out + qrow * DD;
#pragma unroll
  for (int ot = 0; ot < 4; ++ot)
#pragma unroll
    for (int rq = 0; rq < 4; ++rq)
      *(float4*)&orow[ot * 32 + rq * 8 + h * 4] =
          make_float4(oc[ot][rq * 4 + 0], oc[ot][rq * 4 + 1],
                      oc[ot][rq * 4 + 2], oc[ot][rq * 4 + 3]);
}

// ---------------------------------------------------------------------------
extern "C" void kernel_launch(void* const* d_in, const int* in_sizes, int n_in,
                              void* d_out, int out_size, void* d_ws, size_t ws_size,
                              hipStream_t stream) {
  const float* sxyz = (const float*)d_in[0];
  const float* sfeat = (const float*)d_in[1];
  const float* dxyz = (const float*)d_in[2];
  const float* dfeat = (const float*)d_in[3];
  const float* Wq = (const float*)d_in[4];
  const float* bq = (const float*)d_in[5];
  const float* Wk = (const float*)d_in[6];
  const float* bk = (const float*)d_in[7];
  const float* Wv = (const float*)d_in[8];
  const float* bv = (const float*)d_in[9];
  const float* Wo = (const float*)d_in[10];
  const float* bo = (const float*)d_in[11];

  u16* Kws = (u16*)d_ws;                                // NB*N1*DD bf16 = 2MB
  u16* VTws = Kws + (size_t)NB * N1 * DD;               // NB*DD*N1 bf16 = 2MB
  u16* EKws = VTws + (size_t)NB * DD * N1;              // NB*N1*16 bf16 = 256KB

  prep_kv<<<dim3(64), dim3(256), 0, stream>>>(sxyz, sfeat, Wk, bk, Wv, bv, Kws, VTws, EKws);
  attn_fwd<<<dim3(512), dim3(256), 0, stream>>>(dxyz, dfeat, Wq, bq, Wo, bo,
                                                Kws, VTws, EKws, (float*)d_out);
}

// Round 3
// 330.551 us; speedup vs baseline: 1.3689x; 1.3689x over previous
//
// AttentionPropagation — fused bf16-MFMA flash attention for MI355X (gfx950).
//
// R3: R2 minus the unverified v_permlane32_swap (reverted to R1-proven
// __shfl_xor(.,32) partner exchange in conv8).  R2's failure (absmax 0.174 vs
// R1 0.0156) is attributed by elimination to the permlane swap-direction
// convention; all other R2 deltas re-audited clean and kept:
//  1. bf16 packing via native __bf16 casts -> v_cvt_pk_bf16_f32.
//  2. exp2-domain softmax (Q pre-scaled by SCALE*log2e), 1-op v_exp/v_sqrt.
//  3. V^T LDS swizzle (r>>1)&3 — even bank-quad coverage for both lane phases.
//  4. Reg-prefetch staging (T14): tile t+1 global loads issued before tile t
//     compute; ds_write after the read barrier.
//  5. s_setprio(1) around QK/PV MFMA clusters.
// LDS 16KB; grid 512x256; 8 waves/CU structural.

#include <hip/hip_runtime.h>
#include <stdint.h>

#define NB 2
#define N1 4096
#define N2 32768
#define DD 128
#define KT 32
#define NTILES (N1 / KT)
static constexpr float SCLE = 0.1275174306f;         // 128^-0.5 * log2(e)
static constexpr float CNEG = -0.7213475204444817f;  // -0.5 * log2(e)
static constexpr float THR  = 11.5415603f;           // 8 * log2(e) (defer-max, T13)

typedef float f32x16 __attribute__((ext_vector_type(16)));
typedef __bf16 bf16x8v __attribute__((ext_vector_type(8)));
typedef __bf16 bf16x2v __attribute__((ext_vector_type(2)));
typedef unsigned int u32;
typedef unsigned short u16;

union FragU { uint4 u; bf16x8v b; };

__device__ __forceinline__ u16 f2bf(float f) {
  __bf16 h = (__bf16)f;                      // v_cvt RNE
  return __builtin_bit_cast(u16, h);
}
__device__ __forceinline__ u32 pk2(float lo, float hi) {
  bf16x2v v; v[0] = (__bf16)lo; v[1] = (__bf16)hi;  // fuses to v_cvt_pk_bf16_f32
  return __builtin_bit_cast(u32, v);
}
__device__ __forceinline__ float bfhi(float f) {   // float value of bf16(f)
  return (float)(__bf16)f;
}
__device__ __forceinline__ f32x16 MFMA(uint4 a, uint4 b, const f32x16& c) {
  FragU A, B; A.u = a; B.u = b;
  return __builtin_amdgcn_mfma_f32_32x32x16_bf16(A.b, B.b, c, 0, 0, 0);
}
__device__ __forceinline__ uint4 packhi8(float4 a, float4 b) {
  return make_uint4(pk2(a.x, a.y), pk2(a.z, a.w), pk2(b.x, b.y), pk2(b.z, b.w));
}
__device__ __forceinline__ uint4 packlo8(float4 a, float4 b) {
  return make_uint4(pk2(a.x - bfhi(a.x), a.y - bfhi(a.y)),
                    pk2(a.z - bfhi(a.z), a.w - bfhi(a.w)),
                    pk2(b.x - bfhi(b.x), b.y - bfhi(b.y)),
                    pk2(b.z - bfhi(b.z), b.w - bfhi(b.w)));
}
// C-layout 8-reg chunk -> B-fragment for a K=16 MFMA whose contraction rows are
// the C rows (d = (i&3)+8*(i>>2)+4*h).  Partner lanes l, l^32 hold rows 4h..;
// exchange via __shfl_xor(.,32)  (R1-proven; permlane32_swap variant failed R2).
__device__ __forceinline__ uint4 conv8(float a0, float a1, float a2, float a3,
                                       float a4, float a5, float a6, float a7, int h) {
  u32 A0 = pk2(a0, a1), A1 = pk2(a2, a3);
  u32 B0 = pk2(a4, a5), B1 = pk2(a6, a7);
  u32 A0s = (u32)__shfl_xor((int)A0, 32);
  u32 A1s = (u32)__shfl_xor((int)A1, 32);
  u32 B0s = (u32)__shfl_xor((int)B0, 32);
  u32 B1s = (u32)__shfl_xor((int)B1, 32);
  return h ? make_uint4(B0s, B1s, B0, B1) : make_uint4(A0, A1, A0s, A1s);
}

// ---------------------------------------------------------------------------
// prep_kv: K (bf16 row-major), V^T (bf16 [128][4096]), extK into workspace.
// ---------------------------------------------------------------------------
__global__ __launch_bounds__(256) void prep_kv(
    const float* __restrict__ sxyz, const float* __restrict__ sfeat,
    const float* __restrict__ Wk, const float* __restrict__ bk,
    const float* __restrict__ Wv, const float* __restrict__ bv,
    u16* __restrict__ Kws, u16* __restrict__ VTws, u16* __restrict__ EKws) {
  const int tid = threadIdx.x;
  const int l = tid & 63, w = tid >> 6, h = l >> 5, ln = l & 31;
  const int b = blockIdx.x >> 5;           // 32 blocks per batch
  const int kb = (blockIdx.x & 31) * 128;
  const int key = kb + w * 32 + ln;
  const size_t frow = (size_t)(b * N1 + key) * DD;

  uint4 xf[8];
#pragma unroll
  for (int s = 0; s < 8; ++s) {
    const float4* fp = (const float4*)(sfeat + frow + s * 16 + h * 8);
    xf[s] = packhi8(fp[0], fp[1]);
  }
  const float* xp = sxyz + (size_t)(b * N1 + key) * 3;
  float sx = xp[0], sy = xp[1], sz = xp[2];
  uint4 x8 = h ? make_uint4(0, 0, 0, 0)
               : make_uint4(pk2(sx, sy), pk2(sz, 0.f), 0u, 0u);

  f32x16 kacc[4], vacc[4];
#pragma unroll
  for (int ot = 0; ot < 4; ++ot)
#pragma unroll
    for (int r = 0; r < 16; ++r) {
      int o = (r & 3) + 8 * (r >> 2) + 4 * h + 32 * ot;
      kacc[ot][r] = bk[o];
      vacc[ot][r] = bv[o];
    }

#pragma unroll
  for (int ot = 0; ot < 4; ++ot) {
    const int out = ln + 32 * ot;
    const float* wkr = Wk + (size_t)out * 131;
    const float* wvr = Wv + (size_t)out * DD;
#pragma unroll
    for (int s = 0; s < 8; ++s) {
      const float* p = wkr + 3 + s * 16 + h * 8;   // feat weights at cols 3..130
      uint4 wa = make_uint4(pk2(p[0], p[1]), pk2(p[2], p[3]),
                            pk2(p[4], p[5]), pk2(p[6], p[7]));
      kacc[ot] = MFMA(wa, xf[s], kacc[ot]);
      const float4* q = (const float4*)(wvr + s * 16 + h * 8);
      vacc[ot] = MFMA(packhi8(q[0], q[1]), xf[s], vacc[ot]);
    }
    uint4 w8 = h ? make_uint4(0, 0, 0, 0)
                 : make_uint4(pk2(wkr[0], wkr[1]), pk2(wkr[2], 0.f), 0u, 0u);
    kacc[ot] = MFMA(w8, x8, kacc[ot]);
  }

#pragma unroll
  for (int ot = 0; ot < 4; ++ot) {
#pragma unroll
    for (int rq = 0; rq < 4; ++rq) {
      uint2 kv;
      kv.x = pk2(kacc[ot][rq * 4 + 0], kacc[ot][rq * 4 + 1]);
      kv.y = pk2(kacc[ot][rq * 4 + 2], kacc[ot][rq * 4 + 3]);
      *(uint2*)&Kws[(size_t)(b * N1 + key) * DD + ot * 32 + rq * 8 + h * 4] = kv;
    }
#pragma unroll
    for (int r = 0; r < 16; ++r) {
      int o = (r & 3) + 8 * (r >> 2) + 4 * h + 32 * ot;
      VTws[(size_t)(b * DD + o) * N1 + key] = f2bf(vacc[ot][r]);
    }
  }

  if (tid < 128) {
    int k2i = kb + tid;
    const float* xq = sxyz + (size_t)(b * N1 + k2i) * 3;
    float x = xq[0], y = xq[1], z = xq[2];
    float k2 = x * x + y * y + z * z;
    float xh = bfhi(x), xl = x - xh;
    float yh = bfhi(y), yl = y - yh;
    float zh = bfhi(z), zl = z - zh;
    float k2h = bfhi(k2), k2l = k2 - k2h;
    uint4 e0 = make_uint4(pk2(xh, xl), pk2(xh, yh), pk2(yl, yh), pk2(zh, zl));
    uint4 e1 = make_uint4(pk2(zh, k2h), pk2(k2l, 0.f), 0u, 0u);
    uint4* dst = (uint4*)&EKws[(size_t)(b * N1 + k2i) * 16];
    dst[0] = e0;
    dst[1] = e1;
  }
}

// ---------------------------------------------------------------------------
// attn_fwd: fused Q-proj + flash attention + output linear.
// ---------------------------------------------------------------------------
__global__ __launch_bounds__(256, 2) void attn_fwd(
    const float* __restrict__ dxyz, const float* __restrict__ dfeat,
    const float* __restrict__ Wq, const float* __restrict__ bq,
    const float* __restrict__ Wo, const float* __restrict__ bo,
    const u16* __restrict__ Kws, const u16* __restrict__ VTws,
    const u16* __restrict__ EKws, float* __restrict__ out) {
  __shared__ __align__(16) u16 sm[8192];  // [0,4096): K 32x128 ; [4096,8192): V^T 128x32

  const int tid = threadIdx.x;
  const int l = tid & 63, w = tid >> 6, h = l >> 5, ln = l & 31;
  const int b = blockIdx.x >> 8;
  const int qb = (blockIdx.x & 255) * 128;
  const int qi = qb + w * 32 + ln;
  const int bN1 = b * N1;
  const size_t qrow = (size_t)(b * N2 + qi);

  // ---- extQ (distance-bias B-fragment, exact coefficients) + |q|^2
  const float* xp = dxyz + qrow * 3;
  const float qx = xp[0], qy = xp[1], qz = xp[2];
  const float q2 = qx * qx + qy * qy + qz * qz;
  float xh = bfhi(qx), xl = qx - xh, yh = bfhi(qy), yl = qy - yh, zh = bfhi(qz), zl = qz - zh;
  const uint4 eq = h ? make_uint4(pk2(-2.f * zl, 1.f), pk2(1.f, 0.f), 0u, 0u)
                     : make_uint4(pk2(-2.f * xh, -2.f * xh), pk2(-2.f * xl, -2.f * yh),
                                  pk2(-2.f * yh, -2.f * yl), pk2(-2.f * zh, -2.f * zh));

  // ---- Q projection, pre-scaled by SCALE*log2(e) (exp2-domain softmax)
  uint4 qf[8];
  {
    uint4 xf[8];
#pragma unroll
    for (int s = 0; s < 8; ++s) {
      const float4* fp = (const float4*)(dfeat + qrow * DD + s * 16 + h * 8);
      xf[s] = packhi8(fp[0], fp[1]);
    }
    uint4 x8 = h ? make_uint4(0, 0, 0, 0)
                 : make_uint4(pk2(qx, qy), pk2(qz, 0.f), 0u, 0u);
    f32x16 qt[4];
#pragma unroll
    for (int ot = 0; ot < 4; ++ot) {
#pragma unroll
      for (int r = 0; r < 16; ++r)
        qt[ot][r] = SCLE * bq[(r & 3) + 8 * (r >> 2) + 4 * h + 32 * ot];
      const float* wqr = Wq + (size_t)(ln + 32 * ot) * 131;
#pragma unroll
      for (int s = 0; s < 8; ++s) {
        const float* p = wqr + 3 + s * 16 + h * 8;
        uint4 wa = make_uint4(pk2(SCLE * p[0], SCLE * p[1]), pk2(SCLE * p[2], SCLE * p[3]),
                              pk2(SCLE * p[4], SCLE * p[5]), pk2(SCLE * p[6], SCLE * p[7]));
        qt[ot] = MFMA(wa, xf[s], qt[ot]);
      }
      uint4 w8 = h ? make_uint4(0, 0, 0, 0)
                   : make_uint4(pk2(SCLE * wqr[0], SCLE * wqr[1]), pk2(SCLE * wqr[2], 0.f), 0u, 0u);
      qt[ot] = MFMA(w8, x8, qt[ot]);
    }
#pragma unroll
    for (int s = 0; s < 8; ++s) {
      const f32x16& c = qt[s >> 1];
      const int br = (s & 1) * 8;
      qf[s] = conv8(c[br + 0], c[br + 1], c[br + 2], c[br + 3],
                    c[br + 4], c[br + 5], c[br + 6], c[br + 7], h);
    }
  }

  f32x16 oacc[4];
#pragma unroll
  for (int ft = 0; ft < 4; ++ft)
#pragma unroll
    for (int r = 0; r < 16; ++r) oacc[ft][r] = 0.f;
  float m = -1e30f, lsum = 0.f;

  // ---- staging geometry (reg-prefetch, T14)
  const int kr = tid >> 4, kd = tid & 15;
  const int vr = tid >> 2, vd = tid & 3;
  const int kswz = (kd ^ (kr & 7)) * 8;          // (kr+16)&7 == kr&7
  const int vswz = (vd ^ ((vr >> 1) & 3)) * 8;   // ((vr+64)>>1)&3 == (vr>>1)&3
  const int vx = (ln >> 1) & 3;                  // read-side V swizzle
  const u16* Kb = Kws + (size_t)bN1 * DD;
  const u16* Vb = VTws + (size_t)b * DD * N1;
  uint4 k0g, k1g, v0g, v1g;

#define LOADT(kt)                                                            \
  do {                                                                       \
    k0g = *(const uint4*)&Kb[(size_t)((kt) + kr) * DD + kd * 8];             \
    k1g = *(const uint4*)&Kb[(size_t)((kt) + kr + 16) * DD + kd * 8];        \
    v0g = *(const uint4*)&Vb[(size_t)vr * N1 + (kt) + vd * 8];               \
    v1g = *(const uint4*)&Vb[(size_t)(vr + 64) * N1 + (kt) + vd * 8];        \
  } while (0)
#define WRITET()                                                             \
  do {                                                                       \
    *(uint4*)&sm[kr * 128 + kswz] = k0g;                                     \
    *(uint4*)&sm[(kr + 16) * 128 + kswz] = k1g;                              \
    *(uint4*)&sm[4096 + vr * 32 + vswz] = v0g;                               \
    *(uint4*)&sm[4096 + (vr + 64) * 32 + vswz] = v1g;                        \
  } while (0)

  LOADT(0);
  WRITET();
  uint4 ek = *(const uint4*)&EKws[(size_t)(bN1 + ln) * 16 + h * 8];

  for (int t = 0; t < NTILES; ++t) {
    __syncthreads();                      // staged tile visible
    const bool more = (t + 1 < NTILES);
    if (more) LOADT((t + 1) * KT);        // issue early; latency hides under compute

    // ---- distance bias: sq = |q|^2 + |k|^2 - 2 q.k ; bias = -0.5*log2e*dist
    f32x16 sacc;
#pragma unroll
    for (int r = 0; r < 16; ++r) sacc[r] = q2;
    sacc = MFMA(ek, eq, sacc);
#pragma unroll
    for (int r = 0; r < 16; ++r)
      sacc[r] = CNEG * __builtin_amdgcn_sqrtf(fmaxf(sacc[r], 0.f));

    {
      const int ktn = more ? (t + 1) * KT : 0;
      ek = *(const uint4*)&EKws[(size_t)(bN1 + ktn + ln) * 16 + h * 8];
    }

    // ---- S^T = K·Q^T (+bias in C): 8 MFMAs over D=128
    __builtin_amdgcn_s_setprio(1);
#pragma unroll
    for (int kk = 0; kk < 8; ++kk) {
      const uint4 ka = *(const uint4*)&sm[ln * 128 + (((2 * kk + h) ^ (ln & 7)) * 8)];
      sacc = MFMA(ka, qf[kk], sacc);
    }
    __builtin_amdgcn_s_setprio(0);

    // ---- online softmax (exp2 domain; partner lanes l, l^32 share a query)
    float t0 = fmaxf(sacc[0], sacc[1]),   t1 = fmaxf(sacc[2], sacc[3]);
    float t2 = fmaxf(sacc[4], sacc[5]),   t3 = fmaxf(sacc[6], sacc[7]);
    float t4 = fmaxf(sacc[8], sacc[9]),   t5 = fmaxf(sacc[10], sacc[11]);
    float t6 = fmaxf(sacc[12], sacc[13]), t7 = fmaxf(sacc[14], sacc[15]);
    float tmax = fmaxf(fmaxf(fmaxf(t0, t1), fmaxf(t2, t3)),
                       fmaxf(fmaxf(t4, t5), fmaxf(t6, t7)));
    tmax = fmaxf(tmax, __shfl_xor(tmax, 32));
    if (!__all(tmax <= m + THR)) {        // defer-max (T13)
      float nm = fmaxf(m, tmax);
      float f = __builtin_amdgcn_exp2f(m - nm);
      lsum *= f;
#pragma unroll
      for (int ft = 0; ft < 4; ++ft)
#pragma unroll
        for (int r = 0; r < 16; ++r) oacc[ft][r] *= f;
      m = nm;
    }
#pragma unroll
    for (int r = 0; r < 16; ++r) sacc[r] = __builtin_amdgcn_exp2f(sacc[r] - m);
    {
      float s0 = sacc[0] + sacc[1],   s1 = sacc[2] + sacc[3];
      float s2 = sacc[4] + sacc[5],   s3 = sacc[6] + sacc[7];
      float s4 = sacc[8] + sacc[9],   s5 = sacc[10] + sacc[11];
      float s6 = sacc[12] + sacc[13], s7 = sacc[14] + sacc[15];
      lsum += (s0 + s1) + (s2 + s3) + ((s4 + s5) + (s6 + s7));
    }

    // ---- P -> B-frags, then O^T += V^T · P^T
    const uint4 pf0 = conv8(sacc[0], sacc[1], sacc[2], sacc[3],
                            sacc[4], sacc[5], sacc[6], sacc[7], h);
    const uint4 pf1 = conv8(sacc[8], sacc[9], sacc[10], sacc[11],
                            sacc[12], sacc[13], sacc[14], sacc[15], h);
    __builtin_amdgcn_s_setprio(1);
#pragma unroll
    for (int ft = 0; ft < 4; ++ft) {
      const int rr = 32 * ft + ln;
      const uint4 va0 = *(const uint4*)&sm[4096 + rr * 32 + ((h ^ vx) * 8)];
      oacc[ft] = MFMA(va0, pf0, oacc[ft]);
      const uint4 va1 = *(const uint4*)&sm[4096 + rr * 32 + (((2 + h) ^ vx) * 8)];
      oacc[ft] = MFMA(va1, pf1, oacc[ft]);
    }
    __builtin_amdgcn_s_setprio(0);

    __syncthreads();                      // all reads of tile t done
    if (more) WRITET();                   // vmcnt waits here, loads long done
  }
#undef LOADT
#undef WRITET

  // ---- epilogue: out^T = Wo·(O/l) + Wo_h·feat_h + Wo_h·feat_l + Wo_l·feat_h + bo
  lsum += __shfl_xor(lsum, 32);
  const float inv = 1.f / lsum;
#pragma unroll
  for (int ft = 0; ft < 4; ++ft)
#pragma unroll
    for (int r = 0; r < 16; ++r) oacc[ft][r] *= inv;

  f32x16 oc[4];
#pragma unroll
  for (int ot = 0; ot < 4; ++ot)
#pragma unroll
    for (int r = 0; r < 16; ++r)
      oc[ot][r] = bo[(r & 3) + 8 * (r >> 2) + 4 * h + 32 * ot];

#pragma unroll
  for (int s = 0; s < 8; ++s) {
    const f32x16& c = oacc[s >> 1];
    const int br = (s & 1) * 8;
    const uint4 pb = conv8(c[br + 0], c[br + 1], c[br + 2], c[br + 3],
                           c[br + 4], c[br + 5], c[br + 6], c[br + 7], h);
    const float4* fp = (const float4*)(dfeat + qrow * DD + s * 16 + h * 8);
    const float4 fa = fp[0], fb = fp[1];
    const uint4 fh = packhi8(fa, fb);
    const uint4 fl = packlo8(fa, fb);
#pragma unroll
    for (int ot = 0; ot < 4; ++ot) {
      const float4* wp = (const float4*)(Wo + (size_t)(ln + 32 * ot) * DD + s * 16 + h * 8);
      const float4 wa = wp[0], wb = wp[1];
      const uint4 wh = packhi8(wa, wb);
      const uint4 wl = packlo8(wa, wb);
      oc[ot] = MFMA(wh, pb, oc[ot]);
      oc[ot] = MFMA(wh, fh, oc[ot]);
      oc[ot] = MFMA(wh, fl, oc[ot]);
      oc[ot] = MFMA(wl, fh, oc[ot]);
    }
  }

  float* orow = out + qrow * DD;
#pragma unroll
  for (int ot = 0; ot < 4; ++ot)
#pragma unroll
    for (int rq = 0; rq < 4; ++rq)
      *(float4*)&orow[ot * 32 + rq * 8 + h * 4] =
          make_float4(oc[ot][rq * 4 + 0], oc[ot][rq * 4 + 1],
                      oc[ot][rq * 4 + 2], oc[ot][rq * 4 + 3]);
}

// ---------------------------------------------------------------------------
extern "C" void kernel_launch(void* const* d_in, const int* in_sizes, int n_in,
                              void* d_out, int out_size, void* d_ws, size_t ws_size,
                              hipStream_t stream) {
  const float* sxyz = (const float*)d_in[0];
  const float* sfeat = (const float*)d_in[1];
  const float* dxyz = (const float*)d_in[2];
  const float* dfeat = (const float*)d_in[3];
  const float* Wq = (const float*)d_in[4];
  const float* bq = (const float*)d_in[5];
  const float* Wk = (const float*)d_in[6];
  const float* bk = (const float*)d_in[7];
  const float* Wv = (const float*)d_in[8];
  const float* bv = (const float*)d_in[9];
  const float* Wo = (const float*)d_in[10];
  const float* bo = (const float*)d_in[11];

  u16* Kws = (u16*)d_ws;                                // NB*N1*DD bf16 = 2MB
  u16* VTws = Kws + (size_t)NB * N1 * DD;               // NB*DD*N1 bf16 = 2MB
  u16* EKws = VTws + (size_t)NB * DD * N1;              // NB*N1*16 bf16 = 256KB

  prep_kv<<<dim3(64), dim3(256), 0, stream>>>(sxyz, sfeat, Wk, bk, Wv, bv, Kws, VTws, EKws);
  attn_fwd<<<dim3(512), dim3(256), 0, stream>>>(dxyz, dfeat, Wq, bq, Wo, bo,
                                                Kws, VTws, EKws, (float*)d_out);
}